// Round 13
// baseline (54.985 us; speedup 1.0000x reference)
//
#include <hip/hip_runtime.h>

#define IMG 1024
#define RH  16               // output rows per band (16 -> 4 blocks/CU for TLP)
#define NW  4                // waves per block (256 threads, 4 cols/lane = 1024 cols)
#define NEG_INF (-__builtin_inff())
#define PMASK 0x01010101u    // bit0 of each byte = current-row bit plane, byte i = col i of lane

// ---- DPP lane+-1 exchange (wave_shr:1 = 0x138, wave_shl:1 = 0x130) ----
__device__ __forceinline__ unsigned dpp_shr1_u(unsigned x) {   // lane i <- lane i-1 (lane0 -> 0)
    return (unsigned)__builtin_amdgcn_update_dpp(0, (int)x, 0x138, 0xf, 0xf, true);
}
__device__ __forceinline__ unsigned dpp_shl1_u(unsigned x) {   // lane i <- lane i+1 (lane63 -> 0)
    return (unsigned)__builtin_amdgcn_update_dpp(0, (int)x, 0x130, 0xf, 0xf, true);
}
__device__ __forceinline__ float dpp_shr1_f(float x) { return __uint_as_float(dpp_shr1_u(__float_as_uint(x))); }
__device__ __forceinline__ float dpp_shl1_f(float x) { return __uint_as_float(dpp_shl1_u(__float_as_uint(x))); }

__device__ __forceinline__ float max3f(float a, float b, float c) { return fmaxf(fmaxf(a, b), c); }

__device__ __forceinline__ float4 vmax3(float4 a, float4 b, float4 c) {
    return make_float4(max3f(a.x,b.x,c.x), max3f(a.y,b.y,c.y),
                       max3f(a.z,b.z,c.z), max3f(a.w,b.w,c.w));
}

__device__ __forceinline__ float4 hmax3(float4 f, float Lin, float Rin, bool l0, bool l63) {
    float sl = dpp_shr1_f(f.w);
    float sr = dpp_shl1_f(f.x);
    float L = l0 ? Lin : sl;
    float R = l63 ? Rin : sr;
    return make_float4(max3f(L,   f.x, f.y), max3f(f.x, f.y, f.z),
                       max3f(f.y, f.z, f.w), max3f(f.z, f.w, R));
}

__device__ __forceinline__ unsigned hor3(unsigned p, unsigned Lbit, unsigned Rbit, bool l0, bool l63) {
    unsigned sl = dpp_shr1_u(p);
    unsigned sr = dpp_shl1_u(p);
    unsigned L = l0 ? Lbit : ((sl >> 24) & 1u);
    unsigned R = l63 ? Rbit : (sr & 1u);
    return ((p | (p << 8) | (p >> 8)) & PMASK) | L | (R << 24);
}

// equality plane, unguarded (row-validity applied by scalar rvm AND outside)
__device__ __forceinline__ unsigned cmp_plane(float4 a, float4 m) {
    return (a.x == m.x ? 0x1u : 0u) | (a.y == m.y ? 0x100u : 0u) |
           (a.z == m.z ? 0x10000u : 0u) | (a.w == m.w ? 0x1000000u : 0u);
}

// plane already AND'd with row-validity: bit set -> real suppressed pixel -> 0
__device__ __forceinline__ float4 supsel(unsigned plane, float4 v) {
    return make_float4(((plane >>  0) & 1u) ? 0.f : v.x,
                       ((plane >>  8) & 1u) ? 0.f : v.y,
                       ((plane >> 16) & 1u) ? 0.f : v.z,
                       ((plane >> 24) & 1u) ? 0.f : v.w);
}

__device__ __forceinline__ float bsel(unsigned bits, int sh, float v) {
    return ((bits >> sh) & 1u) ? v : 0.f;
}

// scalar (wave-uniform) per-row validity mask
__device__ __forceinline__ unsigned vmask(int r, int lmax) {
    return ((unsigned)r < (unsigned)lmax) ? PMASK : 0u;
}

// LDS-only barrier: orders ds_write -> ds_read without draining vmcnt.
#define LDS_BARRIER() do {                                   \
    __builtin_amdgcn_sched_barrier(0);                       \
    asm volatile("s_waitcnt lgkmcnt(0)" ::: "memory");       \
    __builtin_amdgcn_s_barrier();                            \
    __builtin_amdgcn_sched_barrier(0);                       \
} while (0)

// One pipeline step; K = 0..3 within unrolled group, PAR = (sb+K)&1 (compile-time).
// Arrays: H[i] <-> scores row sb-10+i; SS1[i] <-> ss1 row sb-6+i; SS2[i] <-> ss2 row sb-10+i.
#define STEP(K, PAR) do {                                                               \
    const int s_ = sb + (K);                                                            \
    const float4 pLp = edgeR[(PAR)^1][w];                                               \
    const float4 pRp = edgeL[(PAR)^1][w + 2];                                           \
    const unsigned pLb = __float_as_uint(pLp.w);                                        \
    const unsigned pRb = __float_as_uint(pRp.w);                                        \
    /* S3: hmax(scores) row s-1 */                                                      \
    HV[(K)+2] = hmax3(H[9+(K)], pLp.x, pRp.x, l0, l63);                                 \
    /* S4: m0 row s-2 */                                                                \
    float4 vm0 = vmax3(HV[(K)+2], HV[(K)+1], HV[(K)]);                                  \
    unsigned m0n = cmp_plane(H[8+(K)], vm0) & vmask(s_ - 2, lmax);                      \
    m0h = ((m0h << 1) & ~PMASK) | m0n;                                                  \
    /* S5: hm0 row s-3 */                                                               \
    unsigned hm0n = hor3((m0h >> 1) & PMASK, pLb & 1u, pRb & 1u, l0, l63);              \
    hm0h = ((hm0h << 1) & ~PMASK) | hm0n;                                               \
    /* S6: supp1 row s-4 */                                                             \
    unsigned s1n = (hm0h | (hm0h >> 1) | (hm0h >> 2)) & PMASK;                          \
    s1h = ((s1h << 1) & ~PMASK) | s1n;                                                  \
    /* S7: ss1 row s-4 (kept 2 extra steps; reused at lag 6 instead of recompute) */    \
    SS1[(K)+2] = supsel(s1n & vmask(s_ - 4, lmax), H[6+(K)]);                           \
    /* S8: hmax(ss1) row s-5 */                                                         \
    H1[(K)+2] = hmax3(SS1[(K)+1], pLp.y, pRp.y, l0, l63);                               \
    /* S9: mask1 row s-6 */                                                             \
    float4 vm1 = vmax3(H1[(K)+2], H1[(K)+1], H1[(K)]);                                  \
    unsigned s1l2 = (s1h >> 2) & PMASK;                                                 \
    unsigned rvm6 = vmask(s_ - 6, lmax);                                                \
    unsigned nm1 = cmp_plane(SS1[(K)], vm1) & rvm6;                                     \
    unsigned mk1n = ((m0h >> 4) & PMASK) | (nm1 & ~s1l2);                               \
    mk1h = ((mk1h << 1) & ~PMASK) | mk1n;                                               \
    /* S10: hm1 row s-7 */                                                              \
    unsigned hm1n = hor3((mk1h >> 1) & PMASK, (pLb >> 1) & 1u, (pRb >> 1) & 1u, l0, l63);\
    hm1h = ((hm1h << 1) & ~PMASK) | hm1n;                                               \
    /* S11: supp2 row s-8 */                                                            \
    unsigned s2n = (hm1h | (hm1h >> 1) | (hm1h >> 2)) & PMASK;                          \
    s2h = ((s2h << 1) & ~PMASK) | s2n;                                                  \
    /* S12: ss2 row s-8 (kept 2 extra steps; reused at lag 10) */                       \
    SS2[(K)+2] = supsel(s2n & vmask(s_ - 8, lmax), H[2+(K)]);                           \
    /* S13: hmax(ss2) row s-9 */                                                        \
    H2[(K)+2] = hmax3(SS2[(K)+1], pLp.z, pRp.z, l0, l63);                               \
    /* S14: mask2 + output row s-10 */                                                  \
    float4 vm2 = vmax3(H2[(K)+2], H2[(K)+1], H2[(K)]);                                  \
    unsigned s2l2 = (s2h >> 2) & PMASK;                                                 \
    unsigned rvm10 = vmask(s_ - 10, lmax);                                              \
    unsigned nm2 = cmp_plane(SS2[(K)], vm2) & rvm10;                                    \
    unsigned mk2 = ((mk1h >> 4) & PMASK) | (nm2 & ~s2l2);                               \
    const int srow = s_ - 10;                                                           \
    if (srow >= y0 && srow < yend) {                                                    \
        float4 vv = H[(K)];                                                             \
        outp4[(size_t)srow * (IMG/4) + tid] = make_float4(                              \
            bsel(mk2, 0, vv.x), bsel(mk2, 8, vv.y),                                     \
            bsel(mk2, 16, vv.z), bsel(mk2, 24, vv.w));                                  \
    }                                                                                   \
    unsigned bitsR = ((m0n >> 24) & 1u) | (((mk1n >> 24) & 1u) << 1);                   \
    unsigned bitsL = (m0n & 1u) | ((mk1n & 1u) << 1);                                   \
    if (l63) edgeR[(PAR)][w + 1] = make_float4(H[10+(K)].w, SS1[(K)+2].w, SS2[(K)+2].w, __uint_as_float(bitsR)); \
    if (l0)  edgeL[(PAR)][w + 1] = make_float4(H[10+(K)].x, SS1[(K)+2].x, SS2[(K)+2].x, __uint_as_float(bitsL)); \
    LDS_BARRIER();                                                                      \
} while (0)

__global__ __launch_bounds__(256, 4)
void nms_sweep(const float* __restrict__ in, float* __restrict__ out)
{
    __shared__ float4 edgeR[2][NW + 2];
    __shared__ float4 edgeL[2][NW + 2];

    const int tid  = threadIdx.x;
    const int lane = tid & 63;
    const int w    = tid >> 6;
    const bool l0  = (lane == 0);
    const bool l63 = (lane == 63);
    const int y0   = (int)blockIdx.x * RH;
    const int yend = y0 + RH;
    const size_t base = (size_t)blockIdx.y * ((size_t)IMG * IMG);
    const int lmax = (yend + 5 < IMG) ? yend + 5 : IMG;

    const float4* inp4  = (const float4*)(in + base);
    float4*       outp4 = (float4*)(out + base);

    // init edge slots (both parities) to sentinel {-inf,-inf,-inf,bits=0}
    for (int i = tid; i < 2 * (NW + 2); i += 256) {
        int p = i & 1, sl = i >> 1;
        float4 s = make_float4(NEG_INF, NEG_INF, NEG_INF, __uint_as_float(0u));
        edgeR[p][sl] = s;
        edgeL[p][sl] = s;
    }

    const float4 ninf4 = make_float4(NEG_INF, NEG_INF, NEG_INF, NEG_INF);
    float4 H[14], HV[6], SS1[6], H1[6], SS2[6], H2[6];
#pragma unroll
    for (int i = 0; i < 14; ++i) H[i] = ninf4;
#pragma unroll
    for (int i = 0; i < 6; ++i) { HV[i] = ninf4; H1[i] = ninf4; H2[i] = ninf4; SS1[i] = ninf4; SS2[i] = ninf4; }
    unsigned m0h = 0, hm0h = 0, s1h = 0, mk1h = 0, hm1h = 0, s2h = 0;

    int sb = y0 - 5;   // y0 even -> sb odd -> PAR sequence per group: 1,0,1,0 (static)
    __syncthreads();   // edge-init visibility

    for (int it = 0; it < (RH + 15 + 3) / 4; ++it) {
        // load this group's 4 rows (used from STEP(0)'s edge write onward)
#pragma unroll
        for (int k = 0; k < 4; ++k) {
            const int r = sb + k;
            H[10 + k] = ((unsigned)r < (unsigned)lmax) ? inp4[(size_t)r * (IMG/4) + tid] : ninf4;
        }

        STEP(0, 1);
        STEP(1, 0);
        STEP(2, 1);
        STEP(3, 0);

        // rotate state by 4 rows (static indices -> pure register renames/movs)
#pragma unroll
        for (int i = 0; i < 10; ++i) H[i] = H[i + 4];
        HV[0] = HV[4];   HV[1] = HV[5];
        SS1[0] = SS1[4]; SS1[1] = SS1[5];
        H1[0] = H1[4];   H1[1] = H1[5];
        SS2[0] = SS2[4]; SS2[1] = SS2[5];
        H2[0] = H2[4];   H2[1] = H2[5];
        sb += 4;
    }
}

extern "C" void kernel_launch(void* const* d_in, const int* in_sizes, int n_in,
                              void* d_out, int out_size, void* d_ws, size_t ws_size,
                              hipStream_t stream) {
    const float* in = (const float*)d_in[0];
    float* out = (float*)d_out;
    const int batch = in_sizes[0] / (IMG * IMG);
    dim3 grid(IMG / RH, batch, 1);
    nms_sweep<<<grid, dim3(256, 1, 1), 0, stream>>>(in, out);
}

// Round 14
// 53.092 us; speedup vs baseline: 1.0356x; 1.0356x over previous
//
#include <hip/hip_runtime.h>

#define IMG 1024
#define RH  32               // output rows per wave-band
#define NBANDS (IMG / RH)    // 32
#define NSTRIP 5             // column strips, stride 240, input width 256
#define NEG_INF (-__builtin_inff())
#define PMASK 0x01010101u    // bit0 of each byte = current-row bit plane, byte i = col i of lane

// ---- DPP lane+-1 exchange (wave_shr:1 = 0x138, wave_shl:1 = 0x130) ----
__device__ __forceinline__ unsigned dpp_shr1_u(unsigned x) {   // lane i <- lane i-1 (lane0 -> 0)
    return (unsigned)__builtin_amdgcn_update_dpp(0, (int)x, 0x138, 0xf, 0xf, true);
}
__device__ __forceinline__ unsigned dpp_shl1_u(unsigned x) {   // lane i <- lane i+1 (lane63 -> 0)
    return (unsigned)__builtin_amdgcn_update_dpp(0, (int)x, 0x130, 0xf, 0xf, true);
}
__device__ __forceinline__ float dpp_shr1_f(float x) { return __uint_as_float(dpp_shr1_u(__float_as_uint(x))); }
__device__ __forceinline__ float dpp_shl1_f(float x) { return __uint_as_float(dpp_shl1_u(__float_as_uint(x))); }

__device__ __forceinline__ float max3f(float a, float b, float c) { return fmaxf(fmaxf(a, b), c); }

__device__ __forceinline__ float4 vmax3(float4 a, float4 b, float4 c) {
    return make_float4(max3f(a.x,b.x,c.x), max3f(a.y,b.y,c.y),
                       max3f(a.z,b.z,c.z), max3f(a.w,b.w,c.w));
}

// horizontal 3-max; wave-edge neighbors = -inf (image edge / overwritten halo)
__device__ __forceinline__ float4 hmax3(float4 f, bool l0, bool l63) {
    float sl = dpp_shr1_f(f.w);
    float sr = dpp_shl1_f(f.x);
    float L = l0  ? NEG_INF : sl;
    float R = l63 ? NEG_INF : sr;
    return make_float4(max3f(L,   f.x, f.y), max3f(f.x, f.y, f.z),
                       max3f(f.y, f.z, f.w), max3f(f.z, f.w, R));
}

// horizontal 3-OR on byte-per-col planes; wave-edge bits = 0 (bound_ctrl gives 0)
__device__ __forceinline__ unsigned hor3(unsigned p) {
    unsigned sl = dpp_shr1_u(p);
    unsigned sr = dpp_shl1_u(p);
    return ((p | (p << 8) | (p >> 8)) & PMASK) | ((sl >> 24) & 1u) | ((sr & 1u) << 24);
}

__device__ __forceinline__ unsigned cmp_plane(float4 a, float4 m) {
    return (a.x == m.x ? 0x1u : 0u) | (a.y == m.y ? 0x100u : 0u) |
           (a.z == m.z ? 0x10000u : 0u) | (a.w == m.w ? 0x1000000u : 0u);
}

__device__ __forceinline__ float4 supsel(unsigned plane, float4 v) {
    return make_float4(((plane >>  0) & 1u) ? 0.f : v.x,
                       ((plane >>  8) & 1u) ? 0.f : v.y,
                       ((plane >> 16) & 1u) ? 0.f : v.z,
                       ((plane >> 24) & 1u) ? 0.f : v.w);
}

__device__ __forceinline__ float bsel(unsigned bits, int sh, float v) {
    return ((bits >> sh) & 1u) ? v : 0.f;
}

__device__ __forceinline__ unsigned vmask(int r, int lmax) {
    return ((unsigned)r < (unsigned)lmax) ? PMASK : 0u;
}

// One pipeline step; K = 0..3 within unrolled group (static indices).
// H[i] <-> scores row sb-10+i; SS1[i] <-> ss1 row sb-6+i; SS2[i] <-> ss2 row sb-10+i.
#define STEP(K) do {                                                                    \
    const int s_ = sb + (K);                                                            \
    /* S3: hmax(scores) row s-1 */                                                      \
    HV[(K)+2] = hmax3(H[9+(K)], l0, l63);                                               \
    /* S4: m0 row s-2 */                                                                \
    float4 vm0 = vmax3(HV[(K)+2], HV[(K)+1], HV[(K)]);                                  \
    unsigned m0n = cmp_plane(H[8+(K)], vm0) & vmask(s_ - 2, lmax);                      \
    m0h = ((m0h << 1) & ~PMASK) | m0n;                                                  \
    /* S5: hm0 row s-3 */                                                               \
    unsigned hm0n = hor3((m0h >> 1) & PMASK);                                           \
    hm0h = ((hm0h << 1) & ~PMASK) | hm0n;                                               \
    /* S6: supp1 row s-4 */                                                             \
    unsigned s1n = (hm0h | (hm0h >> 1) | (hm0h >> 2)) & PMASK;                          \
    s1h = ((s1h << 1) & ~PMASK) | s1n;                                                  \
    /* S7: ss1 row s-4 (kept to lag 6; reused instead of recompute) */                  \
    SS1[(K)+2] = supsel(s1n & vmask(s_ - 4, lmax), H[6+(K)]);                           \
    /* S8: hmax(ss1) row s-5 */                                                         \
    H1[(K)+2] = hmax3(SS1[(K)+1], l0, l63);                                             \
    /* S9: mask1 row s-6 */                                                             \
    float4 vm1 = vmax3(H1[(K)+2], H1[(K)+1], H1[(K)]);                                  \
    unsigned s1l2 = (s1h >> 2) & PMASK;                                                 \
    unsigned nm1 = cmp_plane(SS1[(K)], vm1) & vmask(s_ - 6, lmax);                      \
    unsigned mk1n = ((m0h >> 4) & PMASK) | (nm1 & ~s1l2);                               \
    mk1h = ((mk1h << 1) & ~PMASK) | mk1n;                                               \
    /* S10: hm1 row s-7 */                                                              \
    unsigned hm1n = hor3((mk1h >> 1) & PMASK);                                          \
    hm1h = ((hm1h << 1) & ~PMASK) | hm1n;                                               \
    /* S11: supp2 row s-8 */                                                            \
    unsigned s2n = (hm1h | (hm1h >> 1) | (hm1h >> 2)) & PMASK;                          \
    s2h = ((s2h << 1) & ~PMASK) | s2n;                                                  \
    /* S12: ss2 row s-8 (kept to lag 10) */                                             \
    SS2[(K)+2] = supsel(s2n & vmask(s_ - 8, lmax), H[2+(K)]);                           \
    /* S13: hmax(ss2) row s-9 */                                                        \
    H2[(K)+2] = hmax3(SS2[(K)+1], l0, l63);                                             \
    /* S14: mask2 + output row s-10 */                                                  \
    float4 vm2 = vmax3(H2[(K)+2], H2[(K)+1], H2[(K)]);                                  \
    unsigned s2l2 = (s2h >> 2) & PMASK;                                                 \
    unsigned nm2 = cmp_plane(SS2[(K)], vm2) & vmask(s_ - 10, lmax);                     \
    unsigned mk2 = ((mk1h >> 4) & PMASK) | (nm2 & ~s2l2);                               \
    const int srow = s_ - 10;                                                           \
    if (srow >= y0 && srow < yend && ok_lane) {                                         \
        float4 vv = H[(K)];                                                             \
        outp4[(size_t)srow * (IMG/4) + cb4 + lane] = make_float4(                       \
            bsel(mk2, 0, vv.x), bsel(mk2, 8, vv.y),                                     \
            bsel(mk2, 16, vv.z), bsel(mk2, 24, vv.w));                                  \
    }                                                                                   \
} while (0)

__global__ __launch_bounds__(256, 2)
void nms_sweep(const float* __restrict__ in, float* __restrict__ out)
{
    const int tid  = threadIdx.x;
    const int lane = tid & 63;
    const int w    = tid >> 6;
    const bool l0  = (lane == 0);
    const bool l63 = (lane == 63);

    // wave task: wid -> (strip, band); fully independent waves, no LDS, no barriers
    const int wid   = (int)blockIdx.x * 4 + w;           // 0 .. NSTRIP*NBANDS-1
    const int strip = wid / NBANDS;
    const int band  = wid - strip * NBANDS;
    const int y0    = band * RH;
    const int yend  = y0 + RH;
    const int cb    = strip * 240;                        // input col base (aligned)
    const int cb4   = cb >> 2;
    const size_t base = (size_t)blockIdx.y * ((size_t)IMG * IMG);
    const int lmax  = (yend + 5 < IMG) ? yend + 5 : IMG;

    const float4* inp4  = (const float4*)(in + base);
    float4*       outp4 = (float4*)(out + base);

    // per-lane column validity (input) and output-store guard
    const int lc = cb + 4 * lane;                         // this lane's first input col
    const bool col_ok = lc < IMG;
    const int lo_off = (strip == 0) ? 0 : 8;              // output region [cb+lo, cb+hi)
    const int hi_off = (IMG - cb < 248) ? (IMG - cb) : 248;
    const bool ok_lane = (4 * lane >= lo_off) && (4 * lane + 4 <= hi_off);

    const float4 ninf4 = make_float4(NEG_INF, NEG_INF, NEG_INF, NEG_INF);
    float4 H[14], Hn[4], HV[6], SS1[6], H1[6], SS2[6], H2[6];
#pragma unroll
    for (int i = 0; i < 14; ++i) H[i] = ninf4;
#pragma unroll
    for (int i = 0; i < 6; ++i) { HV[i] = ninf4; H1[i] = ninf4; H2[i] = ninf4; SS1[i] = ninf4; SS2[i] = ninf4; }
    unsigned m0h = 0, hm0h = 0, s1h = 0, mk1h = 0, hm1h = 0, s2h = 0;

    int sb = y0 - 5;

    // prologue: group 0 rows
#pragma unroll
    for (int k = 0; k < 4; ++k) {
        const int r = sb + k;
        H[10 + k] = (col_ok && (unsigned)r < (unsigned)lmax) ? inp4[(size_t)r * (IMG/4) + cb4 + lane] : ninf4;
    }

    for (int it = 0; it < (RH + 15 + 3) / 4; ++it) {
        // prefetch next group's rows; no barriers anywhere -> loads stay in flight
#pragma unroll
        for (int k = 0; k < 4; ++k) {
            const int r = sb + 4 + k;
            Hn[k] = (col_ok && (unsigned)r < (unsigned)lmax) ? inp4[(size_t)r * (IMG/4) + cb4 + lane] : ninf4;
        }

        STEP(0);
        STEP(1);
        STEP(2);
        STEP(3);

        // rotate state by 4 rows (static indices)
#pragma unroll
        for (int i = 0; i < 10; ++i) H[i] = H[i + 4];
        H[10] = Hn[0]; H[11] = Hn[1]; H[12] = Hn[2]; H[13] = Hn[3];
        HV[0] = HV[4];   HV[1] = HV[5];
        SS1[0] = SS1[4]; SS1[1] = SS1[5];
        H1[0] = H1[4];   H1[1] = H1[5];
        SS2[0] = SS2[4]; SS2[1] = SS2[5];
        H2[0] = H2[4];   H2[1] = H2[5];
        sb += 4;
    }
}

extern "C" void kernel_launch(void* const* d_in, const int* in_sizes, int n_in,
                              void* d_out, int out_size, void* d_ws, size_t ws_size,
                              hipStream_t stream) {
    const float* in = (const float*)d_in[0];
    float* out = (float*)d_out;
    const int batch = in_sizes[0] / (IMG * IMG);
    dim3 grid((NSTRIP * NBANDS) / 4, batch, 1);   // 4 independent waves per block
    nms_sweep<<<grid, dim3(256, 1, 1), 0, stream>>>(in, out);
}

// Round 15
// 52.921 us; speedup vs baseline: 1.0390x; 1.0032x over previous
//
#include <hip/hip_runtime.h>

#define IMG 1024
#define RH  32               // output rows per wave-band
#define NBANDS (IMG / RH)    // 32
#define NSTRIP 5             // column strips, stride 240, input width 256
#define NEG_INF (-__builtin_inff())
#define PMASK 0x01010101u    // bit0 of each byte = current-row bit plane, byte i = col i of lane

// ---- DPP lane+-1 exchange (wave_shr:1 = 0x138, wave_shl:1 = 0x130) ----
__device__ __forceinline__ unsigned dpp_shr1_u(unsigned x) {   // lane i <- lane i-1 (lane0 -> 0)
    return (unsigned)__builtin_amdgcn_update_dpp(0, (int)x, 0x138, 0xf, 0xf, true);
}
__device__ __forceinline__ unsigned dpp_shl1_u(unsigned x) {   // lane i <- lane i+1 (lane63 -> 0)
    return (unsigned)__builtin_amdgcn_update_dpp(0, (int)x, 0x130, 0xf, 0xf, true);
}
__device__ __forceinline__ float dpp_shr1_f(float x) { return __uint_as_float(dpp_shr1_u(__float_as_uint(x))); }
__device__ __forceinline__ float dpp_shl1_f(float x) { return __uint_as_float(dpp_shl1_u(__float_as_uint(x))); }

__device__ __forceinline__ float max3f(float a, float b, float c) { return fmaxf(fmaxf(a, b), c); }

__device__ __forceinline__ float4 vmax3(float4 a, float4 b, float4 c) {
    return make_float4(max3f(a.x,b.x,c.x), max3f(a.y,b.y,c.y),
                       max3f(a.z,b.z,c.z), max3f(a.w,b.w,c.w));
}

// horizontal 3-max; wave-edge neighbors = -inf (image edge / overwritten halo)
__device__ __forceinline__ float4 hmax3(float4 f, bool l0, bool l63) {
    float sl = dpp_shr1_f(f.w);
    float sr = dpp_shl1_f(f.x);
    float L = l0  ? NEG_INF : sl;
    float R = l63 ? NEG_INF : sr;
    return make_float4(max3f(L,   f.x, f.y), max3f(f.x, f.y, f.z),
                       max3f(f.y, f.z, f.w), max3f(f.z, f.w, R));
}

// horizontal 3-OR on byte-per-col planes; wave-edge bits = 0 (bound_ctrl gives 0)
__device__ __forceinline__ unsigned hor3(unsigned p) {
    unsigned sl = dpp_shr1_u(p);
    unsigned sr = dpp_shl1_u(p);
    return ((p | (p << 8) | (p >> 8)) & PMASK) | ((sl >> 24) & 1u) | ((sr & 1u) << 24);
}

__device__ __forceinline__ unsigned cmp_plane(float4 a, float4 m) {
    return (a.x == m.x ? 0x1u : 0u) | (a.y == m.y ? 0x100u : 0u) |
           (a.z == m.z ? 0x10000u : 0u) | (a.w == m.w ? 0x1000000u : 0u);
}

__device__ __forceinline__ float4 supsel(unsigned plane, float4 v) {
    return make_float4(((plane >>  0) & 1u) ? 0.f : v.x,
                       ((plane >>  8) & 1u) ? 0.f : v.y,
                       ((plane >> 16) & 1u) ? 0.f : v.z,
                       ((plane >> 24) & 1u) ? 0.f : v.w);
}

__device__ __forceinline__ float bsel(unsigned bits, int sh, float v) {
    return ((bits >> sh) & 1u) ? v : 0.f;
}

__device__ __forceinline__ unsigned vmask(int r, int lmax) {
    return ((unsigned)r < (unsigned)lmax) ? PMASK : 0u;
}

// One pipeline step; K = 0..3 within unrolled group (static indices).
// H[i] <-> scores row sb-10+i; SS1[i] <-> ss1 row sb-6+i; SS2[i] <-> ss2 row sb-10+i.
#define STEP(K) do {                                                                    \
    const int s_ = sb + (K);                                                            \
    /* S3: hmax(scores) row s-1 */                                                      \
    HV[(K)+2] = hmax3(H[9+(K)], l0, l63);                                               \
    /* S4: m0 row s-2 */                                                                \
    float4 vm0 = vmax3(HV[(K)+2], HV[(K)+1], HV[(K)]);                                  \
    unsigned m0n = cmp_plane(H[8+(K)], vm0) & vmask(s_ - 2, lmax);                      \
    m0h = ((m0h << 1) & ~PMASK) | m0n;                                                  \
    /* S5: hm0 row s-3 */                                                               \
    unsigned hm0n = hor3((m0h >> 1) & PMASK);                                           \
    hm0h = ((hm0h << 1) & ~PMASK) | hm0n;                                               \
    /* S6: supp1 row s-4 */                                                             \
    unsigned s1n = (hm0h | (hm0h >> 1) | (hm0h >> 2)) & PMASK;                          \
    s1h = ((s1h << 1) & ~PMASK) | s1n;                                                  \
    /* S7: ss1 row s-4 (kept to lag 6; reused instead of recompute) */                  \
    SS1[(K)+2] = supsel(s1n & vmask(s_ - 4, lmax), H[6+(K)]);                           \
    /* S8: hmax(ss1) row s-5 */                                                         \
    H1[(K)+2] = hmax3(SS1[(K)+1], l0, l63);                                             \
    /* S9: mask1 row s-6 */                                                             \
    float4 vm1 = vmax3(H1[(K)+2], H1[(K)+1], H1[(K)]);                                  \
    unsigned s1l2 = (s1h >> 2) & PMASK;                                                 \
    unsigned nm1 = cmp_plane(SS1[(K)], vm1) & vmask(s_ - 6, lmax);                      \
    unsigned mk1n = ((m0h >> 4) & PMASK) | (nm1 & ~s1l2);                               \
    mk1h = ((mk1h << 1) & ~PMASK) | mk1n;                                               \
    /* S10: hm1 row s-7 */                                                              \
    unsigned hm1n = hor3((mk1h >> 1) & PMASK);                                          \
    hm1h = ((hm1h << 1) & ~PMASK) | hm1n;                                               \
    /* S11: supp2 row s-8 */                                                            \
    unsigned s2n = (hm1h | (hm1h >> 1) | (hm1h >> 2)) & PMASK;                          \
    s2h = ((s2h << 1) & ~PMASK) | s2n;                                                  \
    /* S12: ss2 row s-8 (kept to lag 10) */                                             \
    SS2[(K)+2] = supsel(s2n & vmask(s_ - 8, lmax), H[2+(K)]);                           \
    /* S13: hmax(ss2) row s-9 */                                                        \
    H2[(K)+2] = hmax3(SS2[(K)+1], l0, l63);                                             \
    /* S14: mask2 + output row s-10 */                                                  \
    float4 vm2 = vmax3(H2[(K)+2], H2[(K)+1], H2[(K)]);                                  \
    unsigned s2l2 = (s2h >> 2) & PMASK;                                                 \
    unsigned nm2 = cmp_plane(SS2[(K)], vm2) & vmask(s_ - 10, lmax);                     \
    unsigned mk2 = ((mk1h >> 4) & PMASK) | (nm2 & ~s2l2);                               \
    const int srow = s_ - 10;                                                           \
    if (srow >= y0 && srow < yend && ok_lane) {                                         \
        float4 vv = H[(K)];                                                             \
        outp4[(size_t)srow * (IMG/4) + cb4 + lane] = make_float4(                       \
            bsel(mk2, 0, vv.x), bsel(mk2, 8, vv.y),                                     \
            bsel(mk2, 16, vv.z), bsel(mk2, 24, vv.w));                                  \
    }                                                                                   \
} while (0)

__global__ __launch_bounds__(256, 2)
void nms_sweep(const float* __restrict__ in, float* __restrict__ out)
{
    const int tid  = threadIdx.x;
    const int lane = tid & 63;
    const int w    = tid >> 6;
    const bool l0  = (lane == 0);
    const bool l63 = (lane == 63);

    // wave task: wid -> (strip, band); fully independent waves, no LDS, no barriers
    const int wid   = (int)blockIdx.x * 4 + w;           // 0 .. NSTRIP*NBANDS-1
    const int strip = wid / NBANDS;
    const int band  = wid - strip * NBANDS;
    const int y0    = band * RH;
    const int yend  = y0 + RH;
    const int cb    = strip * 240;                        // input col base (aligned)
    const int cb4   = cb >> 2;
    const size_t base = (size_t)blockIdx.y * ((size_t)IMG * IMG);
    const int lmax  = (yend + 5 < IMG) ? yend + 5 : IMG;

    const float4* inp4  = (const float4*)(in + base);
    float4*       outp4 = (float4*)(out + base);

    // per-lane column validity (input) and output-store guard
    const int lc = cb + 4 * lane;                         // this lane's first input col
    const bool col_ok = lc < IMG;
    const int lo_off = (strip == 0) ? 0 : 8;              // output region [cb+lo, cb+hi)
    const int hi_off = (IMG - cb < 248) ? (IMG - cb) : 248;
    const bool ok_lane = (4 * lane >= lo_off) && (4 * lane + 4 <= hi_off);

    const float4 ninf4 = make_float4(NEG_INF, NEG_INF, NEG_INF, NEG_INF);
    float4 H[14], Hn[4], HV[6], SS1[6], H1[6], SS2[6], H2[6];
#pragma unroll
    for (int i = 0; i < 14; ++i) H[i] = ninf4;
#pragma unroll
    for (int i = 0; i < 6; ++i) { HV[i] = ninf4; H1[i] = ninf4; H2[i] = ninf4; SS1[i] = ninf4; SS2[i] = ninf4; }
    unsigned m0h = 0, hm0h = 0, s1h = 0, mk1h = 0, hm1h = 0, s2h = 0;

    int sb = y0 - 5;

    // prologue: group 0 rows
#pragma unroll
    for (int k = 0; k < 4; ++k) {
        const int r = sb + k;
        H[10 + k] = (col_ok && (unsigned)r < (unsigned)lmax) ? inp4[(size_t)r * (IMG/4) + cb4 + lane] : ninf4;
    }

    // I$ experiment: keep the body a LOOP (one 4-step group ~6-7 KB, fits L1I).
    // Full unroll of 12 iterations would stream ~80 KB of code through L1I (32 KB)
    // and cap front-end issue ~50% — the suspected invariant limiter of R7-R14.
#pragma unroll 1
    for (int it = 0; it < (RH + 15 + 3) / 4; ++it) {
        // prefetch next group's rows; no barriers anywhere -> loads stay in flight
#pragma unroll
        for (int k = 0; k < 4; ++k) {
            const int r = sb + 4 + k;
            Hn[k] = (col_ok && (unsigned)r < (unsigned)lmax) ? inp4[(size_t)r * (IMG/4) + cb4 + lane] : ninf4;
        }

        STEP(0);
        STEP(1);
        STEP(2);
        STEP(3);

        // rotate state by 4 rows (static indices)
#pragma unroll
        for (int i = 0; i < 10; ++i) H[i] = H[i + 4];
        H[10] = Hn[0]; H[11] = Hn[1]; H[12] = Hn[2]; H[13] = Hn[3];
        HV[0] = HV[4];   HV[1] = HV[5];
        SS1[0] = SS1[4]; SS1[1] = SS1[5];
        H1[0] = H1[4];   H1[1] = H1[5];
        SS2[0] = SS2[4]; SS2[1] = SS2[5];
        H2[0] = H2[4];   H2[1] = H2[5];
        sb += 4;
    }
}

extern "C" void kernel_launch(void* const* d_in, const int* in_sizes, int n_in,
                              void* d_out, int out_size, void* d_ws, size_t ws_size,
                              hipStream_t stream) {
    const float* in = (const float*)d_in[0];
    float* out = (float*)d_out;
    const int batch = in_sizes[0] / (IMG * IMG);
    dim3 grid((NSTRIP * NBANDS) / 4, batch, 1);   // 4 independent waves per block
    nms_sweep<<<grid, dim3(256, 1, 1), 0, stream>>>(in, out);
}